// Round 4
// baseline (550.855 us; speedup 1.0000x reference)
//
#include <hip/hip_runtime.h>
#include <cmath>

// Temporal Contrast Enhancement — single fused kernel with decoupled lookback.
// x: [8,32,88200] fp32 = 256 series. S=40 divides T -> 2205 chunks/series,
// 9 tiles/series of 256 chunks. Each block: stage tile->LDS ONCE, then run
// all 4 phases (decay-env, attack-env, et-decay-env, final modulation) out of
// LDS. Cross-tile scan state flows via published tile transfers (A,B,G) +
// acquire/release flags; per-phase lookback composes <=8 predecessor
// aggregates. Ticket counter guarantees deadlock-freedom independent of HW
// dispatch order (dependencies always point at smaller tickets; phase-D
// publishes wait on nothing).
// HBM traffic ~ 90MB read + 90MB write (vs 510MB for the 7-kernel pipeline).

static constexpr int   kT   = 88200;
static constexpr float kSR  = 44100.0f;
static constexpr int   kS   = 40;              // samples/chunk (divides kT)
static constexpr int   kS4  = kS / 4;          // float4s per chunk
static constexpr int   kNC  = kT / kS;         // 2205 chunks/series
static constexpr int   kCT  = 256;             // chunks/tile == threads/block
static constexpr int   kNT  = (kNC + kCT - 1) / kCT;   // 9 tiles/series
static constexpr int   kPad = kS + 4;          // padded LDS chunk stride

struct EnvP { float ad, bd, aa, ba, nuamp, reg; };

__device__ __forceinline__ EnvP make_params(const float* tauA, const float* tauD,
                                            const float* nu, const float* dbreg) {
  EnvP p;
  float td = fminf(fmaxf(tauD[0], 1.0f), 100.0f);
  td = fminf(fmaxf(td, 0.1f), 1000.0f) * 0.001f;
  float ta = fminf(fmaxf(tauA[0], 1.0f), 100.0f);
  ta = fminf(fmaxf(ta, 0.1f), 1000.0f) * 0.001f;
  p.ad = expf(-1.0f / (td * kSR));
  p.aa = expf(-1.0f / (ta * kSR));
  p.bd = 1.0f - p.ad;
  p.ba = 1.0f - p.aa;
  p.nuamp = exp10f(fminf(fmaxf(nu[0],    -60.0f),   0.0f) * 0.05f);
  p.reg   = exp10f(fminf(fmaxf(dbreg[0], -120.0f), -60.0f) * 0.05f);
  return p;
}

// Inclusive Hillis-Steele block scan of transfer triples. After return,
// sA/sB/sG hold inclusive prefixes (inactive threads carry identity, so
// slot 255 is the tile aggregate).
template <int ATTACK>
__device__ __forceinline__ void block_scan(float a, float b, float g,
                                           float* sA, float* sB, float* sG, int t) {
  sA[t] = a; sB[t] = b; sG[t] = g;
  __syncthreads();
#pragma unroll
  for (int d = 1; d < 256; d <<= 1) {
    float pa = 0.f, pb = 0.f, pg = 0.f;
    bool has = (t >= d);
    if (has) { pa = sA[t - d]; pb = sB[t - d]; pg = sG[t - d]; }
    __syncthreads();
    if (has) {
      float na = ATTACK ? fminf(a, fmaf(g, pa, b)) : fmaxf(a, fmaf(g, pa, b));
      b = fmaf(g, pb, b);
      g = g * pg;
      a = na;
      sA[t] = a; sB[t] = b; sG[t] = g;
    }
    __syncthreads();
  }
}

__global__ __launch_bounds__(256)
void k_fused(const float* __restrict__ x,
             const float* tauA, const float* tauD,
             const float* nu, const float* dbreg,
             float* __restrict__ out,
             unsigned* __restrict__ tick,
             unsigned* __restrict__ flags,   // [3][NTILES]
             float*    __restrict__ aggs,    // [3][3][NTILES]  (A,B,G per phase)
             int nseries) {
  __shared__ float lds[kCT * kPad];
  __shared__ float sA[256], sB[256], sG[256];
  __shared__ float sIn;
  __shared__ unsigned sVid;

  const int t = threadIdx.x;
  if (t == 0) sVid = atomicAdd(tick, 1u);
  __syncthreads();
  const int vid  = (int)sVid;
  const int tile = vid / nseries;             // low tickets = low tiles
  const int s    = vid - tile * nseries;
  const int NTILES = nseries * kNT;
  const int nchunks = min(kCT, kNC - tile * kCT);   // 256 (or 157 last tile)
  const int n4 = (nchunks * kS) >> 2;
  const size_t gbase = (size_t)s * kT + (size_t)tile * (kCT * kS);

  // ---- stage x tile: coalesced global -> padded LDS ----
  const float4* xg = reinterpret_cast<const float4*>(x + gbase);
  for (int idx = t; idx < n4; idx += 256) {
    float4 v = xg[idx];
    int chunk = idx / kS4;
    int off   = (idx - chunk * kS4) * 4;
    *reinterpret_cast<float4*>(&lds[chunk * kPad + off]) = v;
  }
  __syncthreads();

  const EnvP p = make_params(tauA, tauD, nu, dbreg);
  const bool act = (t < nchunks);
  const float* my = &lds[t * kPad];
  const float gSd = powf(p.ad, (float)kS);
  const float gSa = powf(p.aa, (float)kS);

  float* aggA[3]; float* aggB[3]; float* aggG[3];
#pragma unroll
  for (int ph = 0; ph < 3; ++ph) {
    aggA[ph] = aggs + (size_t)(3 * ph + 0) * NTILES;
    aggB[ph] = aggs + (size_t)(3 * ph + 1) * NTILES;
    aggG[ph] = aggs + (size_t)(3 * ph + 2) * NTILES;
  }
  const int myidx = s * kNT + tile;

  // Publishes tile aggregate (from sA/sB/sG[255]) then lookback-composes the
  // <=8 predecessor aggregates; leaves tile-entry state in sIn.
  auto publish_and_lookback = [&](int ph, int ATTACK) {
    if (t == 0) {
      __hip_atomic_store(&aggA[ph][myidx], sA[255], __ATOMIC_RELAXED, __HIP_MEMORY_SCOPE_AGENT);
      __hip_atomic_store(&aggB[ph][myidx], sB[255], __ATOMIC_RELAXED, __HIP_MEMORY_SCOPE_AGENT);
      __hip_atomic_store(&aggG[ph][myidx], sG[255], __ATOMIC_RELAXED, __HIP_MEMORY_SCOPE_AGENT);
      __hip_atomic_store(&flags[ph * NTILES + myidx], 1u, __ATOMIC_RELEASE, __HIP_MEMORY_SCOPE_AGENT);
      const float ID_A = ATTACK ? INFINITY : -INFINITY;
      float ea = ID_A, eb = 0.f, eg = 1.f;
      for (int k = 0; k < tile; ++k) {
        int idx = s * kNT + k;
        unsigned v = 0; int guard = 0;
        for (;;) {
          v = __hip_atomic_load(&flags[ph * NTILES + idx], __ATOMIC_ACQUIRE, __HIP_MEMORY_SCOPE_AGENT);
          if (v || ++guard > (1 << 18)) break;
          __builtin_amdgcn_s_sleep(8);
        }
        float ka = __hip_atomic_load(&aggA[ph][idx], __ATOMIC_RELAXED, __HIP_MEMORY_SCOPE_AGENT);
        float kb = __hip_atomic_load(&aggB[ph][idx], __ATOMIC_RELAXED, __HIP_MEMORY_SCOPE_AGENT);
        float kg = __hip_atomic_load(&aggG[ph][idx], __ATOMIC_RELAXED, __HIP_MEMORY_SCOPE_AGENT);
        float na = ATTACK ? fminf(ka, fmaf(kg, ea, kb)) : fmaxf(ka, fmaf(kg, ea, kb));
        eb = fmaf(kg, eb, kb);
        eg = kg * eg;
        ea = na;
      }
      sIn = ATTACK ? fminf(ea, eb) : fmaxf(ea, eb);   // series y0 = 0
    }
    __syncthreads();
  };

  // Evaluate this thread's chunk-entry state from its exclusive prefix and
  // the tile-entry state (reads scan LDS; caller must barrier before reuse).
  auto chunk_entry = [&](int ATTACK) -> float {
    float yIn = sIn;
    float ea, eb, eg;
    if (t == 0) { ea = ATTACK ? INFINITY : -INFINITY; eb = 0.f; eg = 1.f; }
    else        { ea = sA[t - 1]; eb = sB[t - 1]; eg = sG[t - 1]; }
    float v = fmaf(eg, yIn, eb);
    return ATTACK ? fminf(ea, v) : fmaxf(ea, v);
  };

  // ================= Phase D: decay env over |x| =================
  float A = -INFINITY, B = 0.f, G = act ? gSd : 1.f;
  if (act) {
#pragma unroll
    for (int i = 0; i < kS4; ++i) {
      float4 v = *reinterpret_cast<const float4*>(&my[4 * i]);
      float vv[4] = {v.x, v.y, v.z, v.w};
#pragma unroll
      for (int j = 0; j < 4; ++j) {
        float xa = fabsf(vv[j]);
        float bx = p.bd * xa;
        A = fmaxf(xa, fmaf(p.ad, A, bx));
        B = fmaf(p.ad, B, bx);
      }
    }
  }
  block_scan<0>(A, B, G, sA, sB, sG, t);
  publish_and_lookback(0, 0);
  const float yd0 = chunk_entry(0);
  __syncthreads();            // protect scan LDS + sIn before next phase

  // ================= Phase A: attack env over yd =================
  A = INFINITY; B = 0.f; G = act ? gSa : 1.f;
  if (act) {
    float yd = yd0;
#pragma unroll
    for (int i = 0; i < kS4; ++i) {
      float4 v = *reinterpret_cast<const float4*>(&my[4 * i]);
      float vv[4] = {v.x, v.y, v.z, v.w};
#pragma unroll
      for (int j = 0; j < 4; ++j) {
        float xa = fabsf(vv[j]);
        yd = fmaxf(xa, fmaf(p.ad, yd, p.bd * xa));
        float by = p.ba * yd;
        A = fminf(yd, fmaf(p.aa, A, by));
        B = fmaf(p.aa, B, by);
      }
    }
  }
  block_scan<1>(A, B, G, sA, sB, sG, t);
  publish_and_lookback(1, 1);
  const float ya0 = chunk_entry(1);
  __syncthreads();

  // ================= Phase E: decay env over et =================
  A = -INFINITY; B = 0.f; G = act ? gSd : 1.f;
  if (act) {
    float yd = yd0, ya = ya0;
#pragma unroll
    for (int i = 0; i < kS4; ++i) {
      float4 v = *reinterpret_cast<const float4*>(&my[4 * i]);
      float vv[4] = {v.x, v.y, v.z, v.w};
#pragma unroll
      for (int j = 0; j < 4; ++j) {
        float xa = fabsf(vv[j]);
        yd = fmaxf(xa, fmaf(p.ad, yd, p.bd * xa));
        ya = fminf(yd, fmaf(p.aa, ya, p.ba * yd));
        float et = fmaxf((yd - ya) - p.nuamp, 0.0f);
        float bx = p.bd * et;
        A = fmaxf(et, fmaf(p.ad, A, bx));
        B = fmaf(p.ad, B, bx);
      }
    }
  }
  block_scan<0>(A, B, G, sA, sB, sG, t);
  publish_and_lookback(2, 0);
  const float ye0 = chunk_entry(0);
  __syncthreads();

  // ================= Final: modulation + store =================
  if (act) {
    float yd = yd0, ya = ya0, ye = ye0;
    float* myw = &lds[t * kPad];
#pragma unroll
    for (int i = 0; i < kS4; ++i) {
      float4 v = *reinterpret_cast<const float4*>(&myw[4 * i]);
      float vv[4] = {v.x, v.y, v.z, v.w};
      float oo[4];
#pragma unroll
      for (int j = 0; j < 4; ++j) {
        float xa = fabsf(vv[j]);
        yd = fmaxf(xa, fmaf(p.ad, yd, p.bd * xa));
        ya = fminf(yd, fmaf(p.aa, ya, p.ba * yd));
        float et = fmaxf((yd - ya) - p.nuamp, 0.0f);
        ye = fmaxf(et, fmaf(p.ad, ye, p.bd * et));
        oo[j] = vv[j] * (et / (ye + p.reg));
      }
      *reinterpret_cast<float4*>(&myw[4 * i]) = make_float4(oo[0], oo[1], oo[2], oo[3]);
    }
  }
  __syncthreads();
  float4* og = reinterpret_cast<float4*>(out + gbase);
  for (int idx = t; idx < n4; idx += 256) {
    int chunk = idx / kS4;
    int off   = (idx - chunk * kS4) * 4;
    og[idx] = *reinterpret_cast<const float4*>(&lds[chunk * kPad + off]);
  }
}

extern "C" void kernel_launch(void* const* d_in, const int* in_sizes, int n_in,
                              void* d_out, int out_size, void* d_ws, size_t ws_size,
                              hipStream_t stream) {
  const float* x     = (const float*)d_in[0];
  const float* tauA  = (const float*)d_in[1];
  const float* tauD  = (const float*)d_in[2];
  const float* nu    = (const float*)d_in[3];
  const float* dbreg = (const float*)d_in[4];
  float* out = (float*)d_out;

  const int nseries = in_sizes[0] / kT;     // 256
  const int NTILES  = nseries * kNT;        // 2304

  // ws layout: [0] ticket | [1 .. 3*NTILES] flags | aggregates (9*NTILES fl)
  unsigned* tick  = (unsigned*)d_ws;
  unsigned* flags = tick + 1;
  float*    aggs  = (float*)(flags + (size_t)3 * NTILES);

  // Zero ticket + flags every call (ws is re-poisoned before each launch).
  hipMemsetAsync(d_ws, 0, sizeof(unsigned) * (1 + (size_t)3 * NTILES), stream);

  k_fused<<<NTILES, 256, 0, stream>>>(x, tauA, tauD, nu, dbreg, out,
                                      tick, flags, aggs, nseries);
}